// Round 10
// baseline (146.187 us; speedup 1.0000x reference)
//
#include <hip/hip_runtime.h>
#include <math.h>

typedef unsigned short u16;
typedef unsigned int u32;
typedef __attribute__((ext_vector_type(8))) short bf16x8;
typedef __attribute__((ext_vector_type(4))) short short4v;
typedef __attribute__((ext_vector_type(4))) float f32x4;

#define HW32 1024
#define HW64 4096
#define KCAM 21
#define PB 32
#define PSPLIT 4
#define FH_STR 136   // u16 LDS row stride (128 + 8 pad): 272B -> conflict-free b128

static __device__ __forceinline__ u16 f2bf(float x) {
  u32 u = __float_as_uint(x);
  u32 r = (u + 0x7FFFu + ((u >> 16) & 1u)) >> 16;
  return (u16)r;
}

// ---------------------------------------------------------------------------
// Kernel A: 1x1 convs at 32x32 (f32). grid (4 ptiles, 2 which x 2 jhalf, 8 n).
// ---------------------------------------------------------------------------
__global__ __launch_bounds__(256) void k_conv32(
    const float* __restrict__ aspp, const float* __restrict__ f3,
    const float* __restrict__ w_aspp, const float* __restrict__ w_f3,
    float* __restrict__ a32, float* __restrict__ g32)
{
  const int pt = blockIdx.x, which = blockIdx.y >> 1, jh = blockIdx.y & 1,
            n = blockIdx.z;
  const float* x = (which == 0 ? aspp : f3) + (size_t)n * 128 * HW32;
  const float* w = (which == 0 ? w_aspp : w_f3) + jh * 32 * 128;
  float* out = (which == 0 ? a32 : g32) + (size_t)n * 64 * HW32 + (size_t)jh * 32 * HW32;

  __shared__ __align__(16) float wlds[32 * 128];
  for (int i = threadIdx.x; i < 32 * 128; i += 256) wlds[i] = w[i];
  __syncthreads();

  const int p = pt * 256 + threadIdx.x;
  float acc[32];
#pragma unroll
  for (int j = 0; j < 32; ++j) acc[j] = 0.f;

  for (int c0 = 0; c0 < 128; c0 += 8) {
    float xv[8];
#pragma unroll
    for (int cc = 0; cc < 8; ++cc) xv[cc] = x[(size_t)(c0 + cc) * HW32 + p];
#pragma unroll
    for (int j = 0; j < 32; ++j) {
      const float4 w0 = *reinterpret_cast<const float4*>(&wlds[j * 128 + c0]);
      const float4 w1 = *reinterpret_cast<const float4*>(&wlds[j * 128 + c0 + 4]);
      acc[j] = fmaf(w0.x, xv[0], acc[j]);
      acc[j] = fmaf(w0.y, xv[1], acc[j]);
      acc[j] = fmaf(w0.z, xv[2], acc[j]);
      acc[j] = fmaf(w0.w, xv[3], acc[j]);
      acc[j] = fmaf(w1.x, xv[4], acc[j]);
      acc[j] = fmaf(w1.y, xv[5], acc[j]);
      acc[j] = fmaf(w1.z, xv[6], acc[j]);
      acc[j] = fmaf(w1.w, xv[7], acc[j]);
    }
  }
  for (int j = 0; j < 32; ++j) out[(size_t)j * HW32 + p] = acc[j];
}

// ---------------------------------------------------------------------------
// Kernel B: build normalized f as bf16 (RN) [n][pos][128] + cam->bf16 side job.
// 512 threads (8 waves): group g=tid>>6 handles 16 output channels.
// Blocks with y<32 also convert camA row y (rows 0..20 cam, 21 ones, rest 0).
// ---------------------------------------------------------------------------
__global__ __launch_bounds__(512) void k_build_f(
    const float* __restrict__ inp, const float* __restrict__ a32,
    const float* __restrict__ g32, const float* __restrict__ w_f9,
    const float* __restrict__ cam,
    u16* __restrict__ fhi_g, u16* __restrict__ camA)
{
  const int y = blockIdx.x, n = blockIdx.y;

  // side job: camA[n][y][*] for y<32 (independent of the rest)
  if (y < 32) {
    const int p = threadIdx.x * 8;
    u16* dst = camA + ((size_t)n * 32 + y) * HW64 + p;
    if (y < KCAM) {
      const float* src = cam + ((size_t)n * KCAM + y) * HW64 + p;
#pragma unroll
      for (int k = 0; k < 8; ++k) dst[k] = f2bf(src[k]);
    } else {
      const u16 v = (y == KCAM) ? f2bf(1.f) : 0;
#pragma unroll
      for (int k = 0; k < 8; ++k) dst[k] = v;
    }
  }

  __shared__ __align__(16) float wlds[128 * 132];
  __shared__ float feat[132 * 64];
  __shared__ float nrm[8][64];

  for (int i = threadIdx.x; i < 128 * 132; i += 512) wlds[i] = w_f9[i];

  const float s512 = 511.f / 63.f, s32 = 31.f / 63.f;
  const float syA = y * s512;
  const int y0A = (int)syA;
  const float wyA = syA - (float)y0A;
  const int y1A = min(y0A + 1, 511);
  const float syB = y * s32;
  const int y0B = (int)syB;
  const float wyB = syB - (float)y0B;
  const int y1B = min(y0B + 1, 31);

  for (int idx = threadIdx.x; idx < 132 * 64; idx += 512) {
    const int c = idx >> 6, x = idx & 63;
    float v;
    if (c < 4) {
      const float sx = x * s512;
      const int x0 = (int)sx;
      const float wx = sx - (float)x0;
      const int x1 = min(x0 + 1, 511);
      const float* im = inp + (size_t)(n * 4 + c) * 512 * 512;
      const float v00 = im[y0A * 512 + x0], v01 = im[y0A * 512 + x1];
      const float v10 = im[y1A * 512 + x0], v11 = im[y1A * 512 + x1];
      v = (v00 * (1.f - wx) + v01 * wx) * (1.f - wyA) +
          (v10 * (1.f - wx) + v11 * wx) * wyA;
    } else {
      const float* im = (c < 68) ? a32 + (size_t)(n * 64 + (c - 4)) * HW32
                                 : g32 + (size_t)(n * 64 + (c - 68)) * HW32;
      const float sx = x * s32;
      const int x0 = (int)sx;
      const float wx = sx - (float)x0;
      const int x1 = min(x0 + 1, 31);
      const float v00 = im[y0B * 32 + x0], v01 = im[y0B * 32 + x1];
      const float v10 = im[y1B * 32 + x0], v11 = im[y1B * 32 + x1];
      v = (v00 * (1.f - wx) + v01 * wx) * (1.f - wyB) +
          (v10 * (1.f - wx) + v11 * wx) * wyB;
    }
    feat[c * 64 + x] = v;
  }
  __syncthreads();

  const int x = threadIdx.x & 63;
  const int g = threadIdx.x >> 6;
  const int og = g * 16;

  float acc[16];
#pragma unroll
  for (int i = 0; i < 16; ++i) acc[i] = 0.f;

  for (int c0 = 0; c0 < 132; c0 += 4) {
    const float f0 = feat[(c0 + 0) * 64 + x];
    const float f1 = feat[(c0 + 1) * 64 + x];
    const float f2 = feat[(c0 + 2) * 64 + x];
    const float f3v = feat[(c0 + 3) * 64 + x];
#pragma unroll
    for (int i = 0; i < 16; ++i) {
      const float4 wv = *reinterpret_cast<const float4*>(&wlds[(og + i) * 132 + c0]);
      acc[i] = fmaf(wv.x, f0, acc[i]);
      acc[i] = fmaf(wv.y, f1, acc[i]);
      acc[i] = fmaf(wv.z, f2, acc[i]);
      acc[i] = fmaf(wv.w, f3v, acc[i]);
    }
  }

  float ss = 0.f;
#pragma unroll
  for (int i = 0; i < 16; ++i) ss = fmaf(acc[i], acc[i], ss);
  nrm[g][x] = ss;
  __syncthreads();
  float tot = 0.f;
#pragma unroll
  for (int gg = 0; gg < 8; ++gg) tot += nrm[gg][x];
  const float inv = 1.f / (sqrtf(tot) + 1e-5f);

  const size_t base = ((size_t)n * HW64 + (size_t)y * 64 + x) * 128 + og;
#pragma unroll
  for (int i = 0; i < 16; ++i) fhi_g[base + i] = f2bf(acc[i] * inv);
}

// ---------------------------------------------------------------------------
// Kernel C: fused affinity+cam, zero-shuffle stage-2 (sigma k-permutation),
// 8 waves/block (each owns 32 q), double-buffered LDS, ONE barrier per tile,
// async-split staging (load early, ds_write late).
// Block = 512 thr; q-range 256/block; p-range 1024 (PSPLIT=4), tiles PB=32.
// grid 512 = 4ps x 16qt x 8n (n in low bits -> XCD L2 locality).
// part layout: [n][ps][22][4096]
// ---------------------------------------------------------------------------
__global__ __launch_bounds__(512, 4) void k_fused(
    const u16* __restrict__ fhi_g, const u16* __restrict__ camA,
    float* __restrict__ part)
{
  __shared__ __align__(16) u16 fh[2][PB * FH_STR];   // 17.4 KB

  const int gx = blockIdx.x;
  const int n = gx & 7;
  const int rest = gx >> 3;
  const int qt = rest & 15;
  const int ps = rest >> 4;
  const int tid = threadIdx.x;
  const int lane = tid & 63;
  const int wave = tid >> 6;            // 0..7
  const int l15 = lane & 15;
  const int l4 = lane >> 4;
  const int qb = qt * 256;

  const u16* fbase = fhi_g + (size_t)n * HW64 * 128;

  // q-side F fragments: wave owns q = qb + wave*32 + qf*16 + l15, qf in {0,1}
  bf16x8 Bq[2][4];
#pragma unroll
  for (int qf = 0; qf < 2; ++qf) {
    const size_t rowo = (size_t)(qb + wave * 32 + qf * 16 + l15) * 128;
#pragma unroll
    for (int s = 0; s < 4; ++s)
      Bq[qf][s] = *(const bf16x8*)(fbase + rowo + s * 32 + l4 * 8);
  }

  f32x4 nacc[2][2];
#pragma unroll
  for (int rt = 0; rt < 2; ++rt)
#pragma unroll
    for (int qf = 0; qf < 2; ++qf) nacc[rt][qf] = {0.f, 0.f, 0.f, 0.f};

  const int p_base = ps * (HW64 / PSPLIT);
  // staging: each thread owns one b128: row sp=tid>>4 (0..31), chunk sc=(tid&15)*8
  const int sp = tid >> 4;
  const int sc = (tid & 15) * 8;
  const int s_lds = sp * FH_STR + sc;

  // prologue: stage tile 0 into buf 0
  {
    const bf16x8 v = *(const bf16x8*)(fbase + (size_t)(p_base + sp) * 128 + sc);
    *(bf16x8*)&fh[0][s_lds] = v;
  }

  int cur = 0;
  for (int t = 0; t < (HW64 / PSPLIT) / PB; ++t) {   // 32 tiles
    const int p0 = p_base + t * PB;
    __syncthreads();                     // buf[cur] staged; buf[cur^1] free

    // issue next tile's global load early (hides L2 latency under compute)
    bf16x8 nxt;
    if (t < 31)
      nxt = *(const bf16x8*)(fbase + (size_t)(p0 + PB + sp) * 128 + sc);

    // ---- Stage 1: S C-frags, K=128
    f32x4 acc[2][2];
#pragma unroll
    for (int pf = 0; pf < 2; ++pf)
#pragma unroll
      for (int qf = 0; qf < 2; ++qf) acc[pf][qf] = {0.f, 0.f, 0.f, 0.f};

#pragma unroll
    for (int s = 0; s < 4; ++s) {
      bf16x8 Ah[2];
#pragma unroll
      for (int pf = 0; pf < 2; ++pf)
        Ah[pf] = *(const bf16x8*)&fh[cur][(pf * 16 + l15) * FH_STR + s * 32 + l4 * 8];
#pragma unroll
      for (int pf = 0; pf < 2; ++pf)
#pragma unroll
        for (int qf = 0; qf < 2; ++qf)
          acc[pf][qf] = __builtin_amdgcn_mfma_f32_16x16x32_bf16(
              Ah[pf], Bq[qf][s], acc[pf][qf], 0, 0, 0);
    }

    // ---- cam A-frags under sigma: two contiguous b64 loads per rt
    bf16x8 Ac[2];
#pragma unroll
    for (int rt = 0; rt < 2; ++rt) {
      union { short4v h[2]; bf16x8 v; } A;
      const u16* cp = camA + ((size_t)n * 32 + rt * 16 + l15) * HW64 + p0 + l4 * 4;
      A.h[0] = *(const short4v*)cp;
      A.h[1] = *(const short4v*)(cp + 16);
      Ac[rt] = A.v;
    }

    // ---- Stage 2: B-frag = own C-frag regs (relu+pack), MFMA K=32
#pragma unroll
    for (int qf = 0; qf < 2; ++qf) {
      const float v0 = fmaxf(acc[0][qf][0], 0.f);
      const float v1 = fmaxf(acc[0][qf][1], 0.f);
      const float v2 = fmaxf(acc[0][qf][2], 0.f);
      const float v3 = fmaxf(acc[0][qf][3], 0.f);
      const float v4 = fmaxf(acc[1][qf][0], 0.f);
      const float v5 = fmaxf(acc[1][qf][1], 0.f);
      const float v6 = fmaxf(acc[1][qf][2], 0.f);
      const float v7 = fmaxf(acc[1][qf][3], 0.f);
      union { u32 d[4]; bf16x8 v; } W;
      asm("v_cvt_pk_bf16_f32 %0, %1, %2" : "=v"(W.d[0]) : "v"(v0), "v"(v1));
      asm("v_cvt_pk_bf16_f32 %0, %1, %2" : "=v"(W.d[1]) : "v"(v2), "v"(v3));
      asm("v_cvt_pk_bf16_f32 %0, %1, %2" : "=v"(W.d[2]) : "v"(v4), "v"(v5));
      asm("v_cvt_pk_bf16_f32 %0, %1, %2" : "=v"(W.d[3]) : "v"(v6), "v"(v7));
      nacc[0][qf] = __builtin_amdgcn_mfma_f32_16x16x32_bf16(Ac[0], W.v, nacc[0][qf], 0, 0, 0);
      nacc[1][qf] = __builtin_amdgcn_mfma_f32_16x16x32_bf16(Ac[1], W.v, nacc[1][qf], 0, 0, 0);
    }

    // ---- late ds_write of next tile into the free buffer
    if (t < 31) *(bf16x8*)&fh[cur ^ 1][s_lds] = nxt;
    cur ^= 1;
  }

  // ---- epilogue: rows = rt*16 + l4*4 + i (<22), cols = q
#pragma unroll
  for (int rt = 0; rt < 2; ++rt)
#pragma unroll
    for (int qf = 0; qf < 2; ++qf) {
      const int qg = qb + wave * 32 + qf * 16 + l15;
#pragma unroll
      for (int i = 0; i < 4; ++i) {
        const int row = rt * 16 + l4 * 4 + i;
        if (row < 22)
          part[(((size_t)n * PSPLIT + ps) * 22 + row) * HW64 + qg] = nacc[rt][qf][i];
      }
    }
}

// ---------------------------------------------------------------------------
// Kernel D: combine PSPLIT partials, divide.
// ---------------------------------------------------------------------------
__global__ __launch_bounds__(256) void k_final(
    const float* __restrict__ part, float* __restrict__ out, int total)
{
  const int idx = blockIdx.x * 256 + threadIdx.x;
  if (idx >= total) return;
  const int n = idx / (KCAM * HW64);
  const int r = idx - n * (KCAM * HW64);
  const int k = r >> 12;
  const int q = r & 4095;
  const float* base = part + (size_t)n * PSPLIT * 22 * HW64;
  float num = 0.f, den = 0.f;
#pragma unroll
  for (int p = 0; p < PSPLIT; ++p) {
    num += base[((size_t)p * 22 + k) * HW64 + q];
    den += base[((size_t)p * 22 + 21) * HW64 + q];
  }
  out[idx] = num / (den + 1e-5f);
}

// ---------------------------------------------------------------------------
extern "C" void kernel_launch(void* const* d_in, const int* in_sizes, int n_in,
                              void* d_out, int out_size, void* d_ws, size_t ws_size,
                              hipStream_t stream) {
  const float* aspp   = (const float*)d_in[0];
  const float* f3     = (const float*)d_in[1];
  const float* inp    = (const float*)d_in[2];
  const float* cam    = (const float*)d_in[3];
  const float* w_aspp = (const float*)d_in[4];
  const float* w_f3   = (const float*)d_in[5];
  const float* w_f9   = (const float*)d_in[6];
  float* out = (float*)d_out;

  // Workspace layout (~21.5 MB):
  //   [0, 8MB)        fhi  (u16, 8*4096*128)      written by k_build_f
  //   [8MB, 10MB)     camA (u16, 8*32*4096)       written by k_build_f (side job)
  //   [10MB, 21.5MB)  part (f32, 8*4*22*4096)     written by k_fused
  //   a32/g32 (2MB each) ALIAS part's first 4MB: produced by k_conv32,
  //   consumed by k_build_f, dead before k_fused writes part (stream-ordered).
  u16*   fhi  = (u16*)d_ws;
  u16*   camA = fhi + 4194304;
  float* part = (float*)(camA + 1048576);
  float* a32  = part;
  float* g32  = a32 + 524288;

  k_conv32<<<dim3(4, 4, 8), 256, 0, stream>>>(aspp, f3, w_aspp, w_f3, a32, g32);
  k_build_f<<<dim3(64, 8), 512, 0, stream>>>(inp, a32, g32, w_f9, cam, fhi, camA);
  k_fused<<<512, 512, 0, stream>>>(fhi, camA, part);
  k_final<<<2688, 256, 0, stream>>>(part, out, 8 * KCAM * HW64);
}

// Round 11
// 117.660 us; speedup vs baseline: 1.2425x; 1.2425x over previous
//
#include <hip/hip_runtime.h>
#include <math.h>

typedef unsigned short u16;
typedef unsigned int u32;
typedef __attribute__((ext_vector_type(8))) short bf16x8;
typedef __attribute__((ext_vector_type(4))) short short4v;
typedef __attribute__((ext_vector_type(4))) float f32x4;

#define HW32 1024
#define HW64 4096
#define KCAM 21
#define PB 32
#define PSPLIT 4
#define FH_STR 136   // u16 LDS row stride (128 + 8 pad): 272B -> conflict-free b128
#define FT_STR 168   // u16 LDS row stride for feat (160 + 8 pad)

static __device__ __forceinline__ u16 f2bf(float x) {
  u32 u = __float_as_uint(x);
  u32 r = (u + 0x7FFFu + ((u >> 16) & 1u)) >> 16;
  return (u16)r;
}
static __device__ __forceinline__ float bf2f(u16 h) {
  return __uint_as_float(((u32)h) << 16);
}

// ---------------------------------------------------------------------------
// Kernel A: 1x1 convs at 32x32 (f32). grid (4 ptiles, 2 which x 2 jhalf, 8 n).
// Side job (blocks with blockIdx.y==0): split w_f9 into padded bf16 hi/lo
// arrays whi/wlo [128][160] (c>=132 zero).
// ---------------------------------------------------------------------------
__global__ __launch_bounds__(256) void k_conv32(
    const float* __restrict__ aspp, const float* __restrict__ f3,
    const float* __restrict__ w_aspp, const float* __restrict__ w_f3,
    const float* __restrict__ w_f9,
    float* __restrict__ a32, float* __restrict__ g32,
    u16* __restrict__ whi, u16* __restrict__ wlo)
{
  const int pt = blockIdx.x, which = blockIdx.y >> 1, jh = blockIdx.y & 1,
            n = blockIdx.z;

  if (blockIdx.y == 0) {   // w_f9 split side job (32 blocks x 256 thr x 3)
    const int bid = blockIdx.z * 4 + blockIdx.x;
#pragma unroll
    for (int k = 0; k < 3; ++k) {
      const int idx = bid * 256 + threadIdx.x + k * 8192;
      if (idx < 128 * 160) {
        const int o = idx / 160, c = idx - o * 160;
        const float v = (c < 132) ? w_f9[o * 132 + c] : 0.f;
        const u16 h = f2bf(v);
        whi[idx] = h;
        wlo[idx] = f2bf(v - bf2f(h));
      }
    }
  }

  const float* x = (which == 0 ? aspp : f3) + (size_t)n * 128 * HW32;
  const float* w = (which == 0 ? w_aspp : w_f3) + jh * 32 * 128;
  float* out = (which == 0 ? a32 : g32) + (size_t)n * 64 * HW32 + (size_t)jh * 32 * HW32;

  __shared__ __align__(16) float wlds[32 * 128];
  for (int i = threadIdx.x; i < 32 * 128; i += 256) wlds[i] = w[i];
  __syncthreads();

  const int p = pt * 256 + threadIdx.x;
  float acc[32];
#pragma unroll
  for (int j = 0; j < 32; ++j) acc[j] = 0.f;

  for (int c0 = 0; c0 < 128; c0 += 8) {
    float xv[8];
#pragma unroll
    for (int cc = 0; cc < 8; ++cc) xv[cc] = x[(size_t)(c0 + cc) * HW32 + p];
#pragma unroll
    for (int j = 0; j < 32; ++j) {
      const float4 w0 = *reinterpret_cast<const float4*>(&wlds[j * 128 + c0]);
      const float4 w1 = *reinterpret_cast<const float4*>(&wlds[j * 128 + c0 + 4]);
      acc[j] = fmaf(w0.x, xv[0], acc[j]);
      acc[j] = fmaf(w0.y, xv[1], acc[j]);
      acc[j] = fmaf(w0.z, xv[2], acc[j]);
      acc[j] = fmaf(w0.w, xv[3], acc[j]);
      acc[j] = fmaf(w1.x, xv[4], acc[j]);
      acc[j] = fmaf(w1.y, xv[5], acc[j]);
      acc[j] = fmaf(w1.z, xv[6], acc[j]);
      acc[j] = fmaf(w1.w, xv[7], acc[j]);
    }
  }
  for (int j = 0; j < 32; ++j) out[(size_t)j * HW32 + p] = acc[j];
}

// ---------------------------------------------------------------------------
// Kernel B: build normalized f via MFMA.
// Block = (y2 in 0..31 -> y rows 2*y2, 2*y2+1; n). 256 thr, 4 waves.
// Phase 1: bilinear-sample feat[128 pos][132 ch] -> LDS bf16 (padded K=160).
// Phase 2: out[128 o][128 pos] = (whi+wlo) @ feat (2-pass MFMA, K=160);
//          per-pos channel-norm via 2x shfl_xor; store bf16 f [n][pos][128].
// Side job: camA row y2 (rows 0..20 = cam bf16, 21 = ones, 22..31 = 0).
// ---------------------------------------------------------------------------
__global__ __launch_bounds__(256) void k_build_f(
    const float* __restrict__ inp, const float* __restrict__ a32,
    const float* __restrict__ g32, const u16* __restrict__ whi,
    const u16* __restrict__ wlo, const float* __restrict__ cam,
    u16* __restrict__ fhi_g, u16* __restrict__ camA)
{
  const int y2 = blockIdx.x, n = blockIdx.y;
  const int tid = threadIdx.x;

  __shared__ __align__(16) u16 feat[128 * FT_STR];   // 42 KB

  // ---- cam side job: camA[n][y2][*]
  {
    u16* dst = camA + ((size_t)n * 32 + y2) * HW64;
    if (y2 < KCAM) {
      const float* src = cam + ((size_t)n * KCAM + y2) * HW64;
      for (int i = tid; i < HW64; i += 256) dst[i] = f2bf(src[i]);
    } else {
      const u16 v = (y2 == KCAM) ? f2bf(1.f) : (u16)0;
      for (int i = tid; i < HW64; i += 256) dst[i] = v;
    }
  }

  // ---- per-row bilinear params (scalars, no runtime-indexed arrays)
  const float s512 = 511.f / 63.f, s32 = 31.f / 63.f;
  const int yA0i = y2 * 2, yA1i = y2 * 2 + 1;
  const float sA0 = yA0i * s512, sA1 = yA1i * s512;
  const int y0A0 = (int)sA0, y0A1 = (int)sA1;
  const float wyA0 = sA0 - y0A0, wyA1 = sA1 - y0A1;
  const int y1A0 = min(y0A0 + 1, 511), y1A1 = min(y0A1 + 1, 511);
  const float sB0 = yA0i * s32, sB1 = yA1i * s32;
  const int y0B0 = (int)sB0, y0B1 = (int)sB1;
  const float wyB0 = sB0 - y0B0, wyB1 = sB1 - y0B1;
  const int y1B0 = min(y0B0 + 1, 31), y1B1 = min(y0B1 + 1, 31);

  // ---- phase 1: feat[pos][c] bf16
  for (int idx = tid; idx < 132 * 128; idx += 256) {
    const int c = idx >> 7;
    const int pos = idx & 127;
    const int ly = pos >> 6, x = pos & 63;
    const int y0A = ly ? y0A1 : y0A0, y1A = ly ? y1A1 : y1A0;
    const float wyA = ly ? wyA1 : wyA0;
    const int y0B = ly ? y0B1 : y0B0, y1B = ly ? y1B1 : y1B0;
    const float wyB = ly ? wyB1 : wyB0;
    float v;
    if (c < 4) {
      const float sx = x * s512;
      const int x0 = (int)sx;
      const float wx = sx - (float)x0;
      const int x1 = min(x0 + 1, 511);
      const float* im = inp + (size_t)(n * 4 + c) * 512 * 512;
      const float v00 = im[y0A * 512 + x0], v01 = im[y0A * 512 + x1];
      const float v10 = im[y1A * 512 + x0], v11 = im[y1A * 512 + x1];
      v = (v00 * (1.f - wx) + v01 * wx) * (1.f - wyA) +
          (v10 * (1.f - wx) + v11 * wx) * wyA;
    } else {
      const float* im = (c < 68) ? a32 + (size_t)(n * 64 + (c - 4)) * HW32
                                 : g32 + (size_t)(n * 64 + (c - 68)) * HW32;
      const float sx = x * s32;
      const int x0 = (int)sx;
      const float wx = sx - (float)x0;
      const int x1 = min(x0 + 1, 31);
      const float v00 = im[y0B * 32 + x0], v01 = im[y0B * 32 + x1];
      const float v10 = im[y1B * 32 + x0], v11 = im[y1B * 32 + x1];
      v = (v00 * (1.f - wx) + v01 * wx) * (1.f - wyB) +
          (v10 * (1.f - wx) + v11 * wx) * wyB;
    }
    feat[pos * FT_STR + c] = f2bf(v);
  }
  // zero-pad channels 132..159
  for (int idx = tid; idx < 28 * 128; idx += 256) {
    const int c = 132 + (idx >> 7), pos = idx & 127;
    feat[pos * FT_STR + c] = 0;
  }
  __syncthreads();

  // ---- phase 2: MFMA, wave owns 32 pos (2 n-frags)
  const int lane = tid & 63, wave = tid >> 6;
  const int l15 = lane & 15, l4 = lane >> 4;

  f32x4 acc[8][2];
#pragma unroll
  for (int m = 0; m < 8; ++m)
#pragma unroll
    for (int nf = 0; nf < 2; ++nf) acc[m][nf] = {0.f, 0.f, 0.f, 0.f};

#pragma unroll
  for (int s = 0; s < 5; ++s) {
    bf16x8 B[2];
#pragma unroll
    for (int nf = 0; nf < 2; ++nf)
      B[nf] = *(const bf16x8*)&feat[(wave * 32 + nf * 16 + l15) * FT_STR +
                                    s * 32 + l4 * 8];
#pragma unroll
    for (int m = 0; m < 8; ++m) {
      const int wo = (m * 16 + l15) * 160 + s * 32 + l4 * 8;
      const bf16x8 Ahi = *(const bf16x8*)(whi + wo);
      const bf16x8 Alo = *(const bf16x8*)(wlo + wo);
#pragma unroll
      for (int nf = 0; nf < 2; ++nf) {
        acc[m][nf] = __builtin_amdgcn_mfma_f32_16x16x32_bf16(Ahi, B[nf], acc[m][nf], 0, 0, 0);
        acc[m][nf] = __builtin_amdgcn_mfma_f32_16x16x32_bf16(Alo, B[nf], acc[m][nf], 0, 0, 0);
      }
    }
  }

  // ---- norm + store: C layout col=l15 (pos), row = m*16 + l4*4 + i (o)
#pragma unroll
  for (int nf = 0; nf < 2; ++nf) {
    float ss = 0.f;
#pragma unroll
    for (int m = 0; m < 8; ++m)
#pragma unroll
      for (int i = 0; i < 4; ++i) ss = fmaf(acc[m][nf][i], acc[m][nf][i], ss);
    ss += __shfl_xor(ss, 16);
    ss += __shfl_xor(ss, 32);
    const float inv = 1.f / (sqrtf(ss) + 1e-5f);
    const int pos = wave * 32 + nf * 16 + l15;
    u16* fp = fhi_g + ((size_t)n * HW64 + (size_t)(y2 * 2 + (pos >> 6)) * 64 +
                       (pos & 63)) * 128 + l4 * 4;
#pragma unroll
    for (int m = 0; m < 8; ++m) {
      const float v0 = acc[m][nf][0] * inv, v1 = acc[m][nf][1] * inv;
      const float v2 = acc[m][nf][2] * inv, v3 = acc[m][nf][3] * inv;
      union { u32 d[2]; short4v h; } P;
      asm("v_cvt_pk_bf16_f32 %0, %1, %2" : "=v"(P.d[0]) : "v"(v0), "v"(v1));
      asm("v_cvt_pk_bf16_f32 %0, %1, %2" : "=v"(P.d[1]) : "v"(v2), "v"(v3));
      *(short4v*)(fp + m * 16) = P.h;
    }
  }
}

// ---------------------------------------------------------------------------
// Kernel C: fused affinity+cam, zero-shuffle stage-2 (sigma k-permutation),
// 4 waves (q64/wave), double-buffered LDS, ONE barrier per tile, async-split
// staging (global load early, ds_write late).
// Block = 256 thr; 256 q/block; p-range 1024 (PSPLIT=4), tiles PB=32.
// grid 512 = 4ps x 16qt x 8n (n in low bits -> XCD L2 locality).
// part layout: [n][ps][22][4096]
// ---------------------------------------------------------------------------
__global__ __launch_bounds__(256) void k_fused(
    const u16* __restrict__ fhi_g, const u16* __restrict__ camA,
    float* __restrict__ part)
{
  __shared__ __align__(16) u16 fh[2][PB * FH_STR];   // 17.4 KB

  const int gx = blockIdx.x;
  const int n = gx & 7;
  const int rest = gx >> 3;
  const int qt = rest & 15;
  const int ps = rest >> 4;
  const int tid = threadIdx.x;
  const int lane = tid & 63;
  const int wq = tid >> 6;
  const int l15 = lane & 15;
  const int l4 = lane >> 4;
  const int qb = qt * 256;

  const u16* fbase = fhi_g + (size_t)n * HW64 * 128;

  // q-side F fragments, resident in VGPRs (64 regs)
  bf16x8 Bq[4][4];
#pragma unroll
  for (int qf = 0; qf < 4; ++qf) {
    const size_t rowo = (size_t)(qb + wq * 64 + qf * 16 + l15) * 128;
#pragma unroll
    for (int s = 0; s < 4; ++s)
      Bq[qf][s] = *(const bf16x8*)(fbase + rowo + s * 32 + l4 * 8);
  }

  f32x4 nacc[2][4];
#pragma unroll
  for (int rt = 0; rt < 2; ++rt)
#pragma unroll
    for (int qf = 0; qf < 4; ++qf) nacc[rt][qf] = {0.f, 0.f, 0.f, 0.f};

  const int p_base = ps * (HW64 / PSPLIT);
  // staging: thread owns two b128: row sp=tid>>3, chunk sc=(tid&7)*16
  const int sp = tid >> 3;
  const int sc = (tid & 7) * 16;
  const int s_lds = sp * FH_STR + sc;

  // prologue: stage tile 0 into buf 0
  {
    const u16* src = fbase + (size_t)(p_base + sp) * 128 + sc;
    *(bf16x8*)&fh[0][s_lds] = *(const bf16x8*)src;
    *(bf16x8*)&fh[0][s_lds + 8] = *(const bf16x8*)(src + 8);
  }

  int cur = 0;
  for (int t = 0; t < (HW64 / PSPLIT) / PB; ++t) {   // 32 tiles
    const int p0 = p_base + t * PB;
    __syncthreads();                     // buf[cur] staged; buf[cur^1] free

    // issue next tile's global loads early (L2 latency hides under compute)
    bf16x8 nxt0, nxt1;
    if (t < 31) {
      const u16* src = fbase + (size_t)(p0 + PB + sp) * 128 + sc;
      nxt0 = *(const bf16x8*)src;
      nxt1 = *(const bf16x8*)(src + 8);
    }

    // ---- Stage 1: S C-frags, K=128
    f32x4 acc[2][4];
#pragma unroll
    for (int pf = 0; pf < 2; ++pf)
#pragma unroll
      for (int qf = 0; qf < 4; ++qf) acc[pf][qf] = {0.f, 0.f, 0.f, 0.f};

#pragma unroll
    for (int s = 0; s < 4; ++s) {
      bf16x8 Ah[2];
#pragma unroll
      for (int pf = 0; pf < 2; ++pf)
        Ah[pf] = *(const bf16x8*)&fh[cur][(pf * 16 + l15) * FH_STR + s * 32 + l4 * 8];
#pragma unroll
      for (int pf = 0; pf < 2; ++pf)
#pragma unroll
        for (int qf = 0; qf < 4; ++qf)
          acc[pf][qf] = __builtin_amdgcn_mfma_f32_16x16x32_bf16(
              Ah[pf], Bq[qf][s], acc[pf][qf], 0, 0, 0);
    }

    // ---- cam A-frags under sigma: two contiguous b64 loads per rt
    bf16x8 Ac[2];
#pragma unroll
    for (int rt = 0; rt < 2; ++rt) {
      union { short4v h[2]; bf16x8 v; } A;
      const u16* cp = camA + ((size_t)n * 32 + rt * 16 + l15) * HW64 + p0 + l4 * 4;
      A.h[0] = *(const short4v*)cp;
      A.h[1] = *(const short4v*)(cp + 16);
      Ac[rt] = A.v;
    }

    // ---- Stage 2: B-frag = own C-frag regs (relu+pack), MFMA K=32
#pragma unroll
    for (int qf = 0; qf < 4; ++qf) {
      const float v0 = fmaxf(acc[0][qf][0], 0.f);
      const float v1 = fmaxf(acc[0][qf][1], 0.f);
      const float v2 = fmaxf(acc[0][qf][2], 0.f);
      const float v3 = fmaxf(acc[0][qf][3], 0.f);
      const float v4 = fmaxf(acc[1][qf][0], 0.f);
      const float v5 = fmaxf(acc[1][qf][1], 0.f);
      const float v6 = fmaxf(acc[1][qf][2], 0.f);
      const float v7 = fmaxf(acc[1][qf][3], 0.f);
      union { u32 d[4]; bf16x8 v; } W;
      asm("v_cvt_pk_bf16_f32 %0, %1, %2" : "=v"(W.d[0]) : "v"(v0), "v"(v1));
      asm("v_cvt_pk_bf16_f32 %0, %1, %2" : "=v"(W.d[1]) : "v"(v2), "v"(v3));
      asm("v_cvt_pk_bf16_f32 %0, %1, %2" : "=v"(W.d[2]) : "v"(v4), "v"(v5));
      asm("v_cvt_pk_bf16_f32 %0, %1, %2" : "=v"(W.d[3]) : "v"(v6), "v"(v7));
      nacc[0][qf] = __builtin_amdgcn_mfma_f32_16x16x32_bf16(Ac[0], W.v, nacc[0][qf], 0, 0, 0);
      nacc[1][qf] = __builtin_amdgcn_mfma_f32_16x16x32_bf16(Ac[1], W.v, nacc[1][qf], 0, 0, 0);
    }

    // ---- late ds_write of next tile into the free buffer
    if (t < 31) {
      *(bf16x8*)&fh[cur ^ 1][s_lds] = nxt0;
      *(bf16x8*)&fh[cur ^ 1][s_lds + 8] = nxt1;
    }
    cur ^= 1;
  }

  // ---- epilogue: rows = rt*16 + l4*4 + i (<22), cols = q
#pragma unroll
  for (int rt = 0; rt < 2; ++rt)
#pragma unroll
    for (int qf = 0; qf < 4; ++qf) {
      const int qg = qb + wq * 64 + qf * 16 + l15;
#pragma unroll
      for (int i = 0; i < 4; ++i) {
        const int row = rt * 16 + l4 * 4 + i;
        if (row < 22)
          part[(((size_t)n * PSPLIT + ps) * 22 + row) * HW64 + qg] = nacc[rt][qf][i];
      }
    }
}

// ---------------------------------------------------------------------------
// Kernel D: combine PSPLIT partials, divide.
// ---------------------------------------------------------------------------
__global__ __launch_bounds__(256) void k_final(
    const float* __restrict__ part, float* __restrict__ out, int total)
{
  const int idx = blockIdx.x * 256 + threadIdx.x;
  if (idx >= total) return;
  const int n = idx / (KCAM * HW64);
  const int r = idx - n * (KCAM * HW64);
  const int k = r >> 12;
  const int q = r & 4095;
  const float* base = part + (size_t)n * PSPLIT * 22 * HW64;
  float num = 0.f, den = 0.f;
#pragma unroll
  for (int p = 0; p < PSPLIT; ++p) {
    num += base[((size_t)p * 22 + k) * HW64 + q];
    den += base[((size_t)p * 22 + 21) * HW64 + q];
  }
  out[idx] = num / (den + 1e-5f);
}

// ---------------------------------------------------------------------------
extern "C" void kernel_launch(void* const* d_in, const int* in_sizes, int n_in,
                              void* d_out, int out_size, void* d_ws, size_t ws_size,
                              hipStream_t stream) {
  const float* aspp   = (const float*)d_in[0];
  const float* f3     = (const float*)d_in[1];
  const float* inp    = (const float*)d_in[2];
  const float* cam    = (const float*)d_in[3];
  const float* w_aspp = (const float*)d_in[4];
  const float* w_f3   = (const float*)d_in[5];
  const float* w_f9   = (const float*)d_in[6];
  float* out = (float*)d_out;

  // Workspace (~21.7 MB):
  //   [0, 8MB)           fhi  (u16, 8*4096*128)   k_build_f
  //   [8MB, 10MB)        camA (u16, 8*32*4096)    k_build_f side job
  //   [10MB, +80KB)      whi  (u16, 128*160)      k_conv32 side job
  //   [.., +80KB)        wlo  (u16, 128*160)
  //   then part (f32, 8*4*22*4096 = 11.5MB)       k_fused
  //   a32/g32 (2MB each) ALIAS part: produced by k_conv32, consumed by
  //   k_build_f, dead before k_fused writes part (stream-ordered).
  u16*   fhi  = (u16*)d_ws;
  u16*   camA = fhi + 4194304;
  u16*   whi  = camA + 1048576;
  u16*   wlo  = whi + 20480;
  float* part = (float*)(wlo + 20480);
  float* a32  = part;
  float* g32  = a32 + 524288;

  k_conv32<<<dim3(4, 4, 8), 256, 0, stream>>>(aspp, f3, w_aspp, w_f3, w_f9,
                                              a32, g32, whi, wlo);
  k_build_f<<<dim3(32, 8), 256, 0, stream>>>(inp, a32, g32, whi, wlo, cam,
                                             fhi, camA);
  k_fused<<<512, 256, 0, stream>>>(fhi, camA, part);
  k_final<<<2688, 256, 0, stream>>>(part, out, 8 * KCAM * HW64);
}

// Round 12
// 112.281 us; speedup vs baseline: 1.3020x; 1.0479x over previous
//
#include <hip/hip_runtime.h>
#include <math.h>

typedef unsigned short u16;
typedef unsigned int u32;
typedef __attribute__((ext_vector_type(8))) short bf16x8;
typedef __attribute__((ext_vector_type(4))) short short4v;
typedef __attribute__((ext_vector_type(4))) float f32x4;
typedef __attribute__((ext_vector_type(16))) float f32x16;

#define HW32 1024
#define HW64 4096
#define KCAM 21
#define PB 32
#define PSPLIT 4
#define FT_STR 168   // u16 LDS row stride for feat (160 + 8 pad)

static __device__ __forceinline__ u16 f2bf(float x) {
  u32 u = __float_as_uint(x);
  u32 r = (u + 0x7FFFu + ((u >> 16) & 1u)) >> 16;
  return (u16)r;
}
static __device__ __forceinline__ float bf2f(u16 h) {
  return __uint_as_float(((u32)h) << 16);
}

// ---------------------------------------------------------------------------
// Kernel A: 1x1 convs at 32x32 (f32). grid (4 ptiles, 2 which x 2 jhalf, 8 n).
// Side job (blockIdx.y==0): split w_f9 into padded bf16 hi/lo [128][160].
// ---------------------------------------------------------------------------
__global__ __launch_bounds__(256) void k_conv32(
    const float* __restrict__ aspp, const float* __restrict__ f3,
    const float* __restrict__ w_aspp, const float* __restrict__ w_f3,
    const float* __restrict__ w_f9,
    float* __restrict__ a32, float* __restrict__ g32,
    u16* __restrict__ whi, u16* __restrict__ wlo)
{
  const int pt = blockIdx.x, which = blockIdx.y >> 1, jh = blockIdx.y & 1,
            n = blockIdx.z;

  if (blockIdx.y == 0) {   // w_f9 split side job
    const int bid = blockIdx.z * 4 + blockIdx.x;
#pragma unroll
    for (int k = 0; k < 3; ++k) {
      const int idx = bid * 256 + threadIdx.x + k * 8192;
      if (idx < 128 * 160) {
        const int o = idx / 160, c = idx - o * 160;
        const float v = (c < 132) ? w_f9[o * 132 + c] : 0.f;
        const u16 h = f2bf(v);
        whi[idx] = h;
        wlo[idx] = f2bf(v - bf2f(h));
      }
    }
  }

  const float* x = (which == 0 ? aspp : f3) + (size_t)n * 128 * HW32;
  const float* w = (which == 0 ? w_aspp : w_f3) + jh * 32 * 128;
  float* out = (which == 0 ? a32 : g32) + (size_t)n * 64 * HW32 + (size_t)jh * 32 * HW32;

  __shared__ __align__(16) float wlds[32 * 128];
  for (int i = threadIdx.x; i < 32 * 128; i += 256) wlds[i] = w[i];
  __syncthreads();

  const int p = pt * 256 + threadIdx.x;
  float acc[32];
#pragma unroll
  for (int j = 0; j < 32; ++j) acc[j] = 0.f;

  for (int c0 = 0; c0 < 128; c0 += 8) {
    float xv[8];
#pragma unroll
    for (int cc = 0; cc < 8; ++cc) xv[cc] = x[(size_t)(c0 + cc) * HW32 + p];
#pragma unroll
    for (int j = 0; j < 32; ++j) {
      const float4 w0 = *reinterpret_cast<const float4*>(&wlds[j * 128 + c0]);
      const float4 w1 = *reinterpret_cast<const float4*>(&wlds[j * 128 + c0 + 4]);
      acc[j] = fmaf(w0.x, xv[0], acc[j]);
      acc[j] = fmaf(w0.y, xv[1], acc[j]);
      acc[j] = fmaf(w0.z, xv[2], acc[j]);
      acc[j] = fmaf(w0.w, xv[3], acc[j]);
      acc[j] = fmaf(w1.x, xv[4], acc[j]);
      acc[j] = fmaf(w1.y, xv[5], acc[j]);
      acc[j] = fmaf(w1.z, xv[6], acc[j]);
      acc[j] = fmaf(w1.w, xv[7], acc[j]);
    }
  }
  for (int j = 0; j < 32; ++j) out[(size_t)j * HW32 + p] = acc[j];
}

// ---------------------------------------------------------------------------
// Kernel B: build normalized f via MFMA (unchanged from R11).
// ---------------------------------------------------------------------------
__global__ __launch_bounds__(256) void k_build_f(
    const float* __restrict__ inp, const float* __restrict__ a32,
    const float* __restrict__ g32, const u16* __restrict__ whi,
    const u16* __restrict__ wlo, const float* __restrict__ cam,
    u16* __restrict__ fhi_g, u16* __restrict__ camA)
{
  const int y2 = blockIdx.x, n = blockIdx.y;
  const int tid = threadIdx.x;

  __shared__ __align__(16) u16 feat[128 * FT_STR];   // 42 KB

  {
    u16* dst = camA + ((size_t)n * 32 + y2) * HW64;
    if (y2 < KCAM) {
      const float* src = cam + ((size_t)n * KCAM + y2) * HW64;
      for (int i = tid; i < HW64; i += 256) dst[i] = f2bf(src[i]);
    } else {
      const u16 v = (y2 == KCAM) ? f2bf(1.f) : (u16)0;
      for (int i = tid; i < HW64; i += 256) dst[i] = v;
    }
  }

  const float s512 = 511.f / 63.f, s32 = 31.f / 63.f;
  const int yA0i = y2 * 2, yA1i = y2 * 2 + 1;
  const float sA0 = yA0i * s512, sA1 = yA1i * s512;
  const int y0A0 = (int)sA0, y0A1 = (int)sA1;
  const float wyA0 = sA0 - y0A0, wyA1 = sA1 - y0A1;
  const int y1A0 = min(y0A0 + 1, 511), y1A1 = min(y0A1 + 1, 511);
  const float sB0 = yA0i * s32, sB1 = yA1i * s32;
  const int y0B0 = (int)sB0, y0B1 = (int)sB1;
  const float wyB0 = sB0 - y0B0, wyB1 = sB1 - y0B1;
  const int y1B0 = min(y0B0 + 1, 31), y1B1 = min(y0B1 + 1, 31);

  for (int idx = tid; idx < 132 * 128; idx += 256) {
    const int c = idx >> 7;
    const int pos = idx & 127;
    const int ly = pos >> 6, x = pos & 63;
    const int y0A = ly ? y0A1 : y0A0, y1A = ly ? y1A1 : y1A0;
    const float wyA = ly ? wyA1 : wyA0;
    const int y0B = ly ? y0B1 : y0B0, y1B = ly ? y1B1 : y1B0;
    const float wyB = ly ? wyB1 : wyB0;
    float v;
    if (c < 4) {
      const float sx = x * s512;
      const int x0 = (int)sx;
      const float wx = sx - (float)x0;
      const int x1 = min(x0 + 1, 511);
      const float* im = inp + (size_t)(n * 4 + c) * 512 * 512;
      const float v00 = im[y0A * 512 + x0], v01 = im[y0A * 512 + x1];
      const float v10 = im[y1A * 512 + x0], v11 = im[y1A * 512 + x1];
      v = (v00 * (1.f - wx) + v01 * wx) * (1.f - wyA) +
          (v10 * (1.f - wx) + v11 * wx) * wyA;
    } else {
      const float* im = (c < 68) ? a32 + (size_t)(n * 64 + (c - 4)) * HW32
                                 : g32 + (size_t)(n * 64 + (c - 68)) * HW32;
      const float sx = x * s32;
      const int x0 = (int)sx;
      const float wx = sx - (float)x0;
      const int x1 = min(x0 + 1, 31);
      const float v00 = im[y0B * 32 + x0], v01 = im[y0B * 32 + x1];
      const float v10 = im[y1B * 32 + x0], v11 = im[y1B * 32 + x1];
      v = (v00 * (1.f - wx) + v01 * wx) * (1.f - wyB) +
          (v10 * (1.f - wx) + v11 * wx) * wyB;
    }
    feat[pos * FT_STR + c] = f2bf(v);
  }
  for (int idx = tid; idx < 28 * 128; idx += 256) {
    const int c = 132 + (idx >> 7), pos = idx & 127;
    feat[pos * FT_STR + c] = 0;
  }
  __syncthreads();

  const int lane = tid & 63, wave = tid >> 6;
  const int l15 = lane & 15, l4 = lane >> 4;

  f32x4 acc[8][2];
#pragma unroll
  for (int m = 0; m < 8; ++m)
#pragma unroll
    for (int nf = 0; nf < 2; ++nf) acc[m][nf] = {0.f, 0.f, 0.f, 0.f};

#pragma unroll
  for (int s = 0; s < 5; ++s) {
    bf16x8 B[2];
#pragma unroll
    for (int nf = 0; nf < 2; ++nf)
      B[nf] = *(const bf16x8*)&feat[(wave * 32 + nf * 16 + l15) * FT_STR +
                                    s * 32 + l4 * 8];
#pragma unroll
    for (int m = 0; m < 8; ++m) {
      const int wo = (m * 16 + l15) * 160 + s * 32 + l4 * 8;
      const bf16x8 Ahi = *(const bf16x8*)(whi + wo);
      const bf16x8 Alo = *(const bf16x8*)(wlo + wo);
#pragma unroll
      for (int nf = 0; nf < 2; ++nf) {
        acc[m][nf] = __builtin_amdgcn_mfma_f32_16x16x32_bf16(Ahi, B[nf], acc[m][nf], 0, 0, 0);
        acc[m][nf] = __builtin_amdgcn_mfma_f32_16x16x32_bf16(Alo, B[nf], acc[m][nf], 0, 0, 0);
      }
    }
  }

#pragma unroll
  for (int nf = 0; nf < 2; ++nf) {
    float ss = 0.f;
#pragma unroll
    for (int m = 0; m < 8; ++m)
#pragma unroll
      for (int i = 0; i < 4; ++i) ss = fmaf(acc[m][nf][i], acc[m][nf][i], ss);
    ss += __shfl_xor(ss, 16);
    ss += __shfl_xor(ss, 32);
    const float inv = 1.f / (sqrtf(ss) + 1e-5f);
    const int pos = wave * 32 + nf * 16 + l15;
    u16* fp = fhi_g + ((size_t)n * HW64 + (size_t)(y2 * 2 + (pos >> 6)) * 64 +
                       (pos & 63)) * 128 + l4 * 4;
#pragma unroll
    for (int m = 0; m < 8; ++m) {
      const float v0 = acc[m][nf][0] * inv, v1 = acc[m][nf][1] * inv;
      const float v2 = acc[m][nf][2] * inv, v3 = acc[m][nf][3] * inv;
      union { u32 d[2]; short4v h; } P;
      asm("v_cvt_pk_bf16_f32 %0, %1, %2" : "=v"(P.d[0]) : "v"(v0), "v"(v1));
      asm("v_cvt_pk_bf16_f32 %0, %1, %2" : "=v"(P.d[1]) : "v"(v2), "v"(v3));
      *(short4v*)(fp + m * 16) = P.h;
    }
  }
}

// ---------------------------------------------------------------------------
// Kernel C: fused affinity+cam on 32x32x16 MFMA, zero-shuffle stage-2.
// Stage1: S[32p x 64q] per wave = 16 MFMA (2 q-halves x 8 ksteps), A from
//   XOR-swizzled LDS (conflict-free), B (F_q) resident in VGPRs.
// C layout (m74-verified): col=lane&31, row R(r)=(r&3)+8*(r>>2)+4*(lane>>5).
// Stage2 k-permutation pi per 16-kstep: {0-3,8-11 | 4-7,12-15} (lane-half) ->
//   B-frag = own acc regs 0..7 / 8..15 (relu+cvt_pk, zero cross-lane);
//   cam A-frag absorbs pi as two contiguous b64 loads; cam's 32 rows = one
//   32x32 output tile (rows 22..31 zero-padded).
// Block 256 thr / 4 waves (q64 each); PB=32, PSPLIT=4; grid 512 = 4ps x 16qt
// x 8n (n low bits -> XCD L2). Double-buffered LDS, one barrier/tile,
// async-split staging. part layout: [n][ps][22][4096].
// ---------------------------------------------------------------------------
__global__ __launch_bounds__(256) void k_fused(
    const u16* __restrict__ fhi_g, const u16* __restrict__ camA,
    float* __restrict__ part)
{
  __shared__ __align__(16) u16 fh[2][PB * 128];   // 16 KB, XOR-swizzled

  const int gx = blockIdx.x;
  const int n = gx & 7;
  const int rest = gx >> 3;
  const int qt = rest & 15;
  const int ps = rest >> 4;
  const int tid = threadIdx.x;
  const int lane = tid & 63;
  const int wq = tid >> 6;
  const int l31 = lane & 31;
  const int lh = lane >> 5;            // 0/1
  const int qb = qt * 256;

  const u16* fbase = fhi_g + (size_t)n * HW64 * 128;

  // q-side F fragments (B operand), resident: 16 x 4 = 64 VGPRs
  bf16x8 Bq[2][8];
#pragma unroll
  for (int qh = 0; qh < 2; ++qh) {
    const size_t rowo = (size_t)(qb + wq * 64 + qh * 32 + l31) * 128;
#pragma unroll
    for (int ks = 0; ks < 8; ++ks)
      Bq[qh][ks] = *(const bf16x8*)(fbase + rowo + ks * 16 + lh * 8);
  }

  f32x16 nacc[2];
#pragma unroll
  for (int qh = 0; qh < 2; ++qh)
#pragma unroll
    for (int i = 0; i < 16; ++i) nacc[qh][i] = 0.f;

  const int p_base = ps * (HW64 / PSPLIT);
  // staging: thread owns 32B of row sp: two swizzled 16B chunks
  const int sp = tid >> 3;
  const int scb = (tid & 7) * 32;                  // byte col
  const int xorw = (sp & 7) << 4;
  const int w0 = sp * 128 + (((scb) ^ xorw) >> 1);
  const int w1 = sp * 128 + (((scb + 16) ^ xorw) >> 1);
  const int xorr = (l31 & 7) << 4;
  const int rowbase = l31 * 128;

  // prologue: stage tile 0 into buf 0
  {
    const u16* src = fbase + (size_t)(p_base + sp) * 128 + scb / 2;
    *(bf16x8*)&fh[0][w0] = *(const bf16x8*)src;
    *(bf16x8*)&fh[0][w1] = *(const bf16x8*)(src + 8);
  }

  int cur = 0;
  for (int t = 0; t < (HW64 / PSPLIT) / PB; ++t) {   // 32 tiles
    const int p0 = p_base + t * PB;
    __syncthreads();

    bf16x8 nxt0, nxt1;
    if (t < 31) {
      const u16* src = fbase + (size_t)(p0 + PB + sp) * 128 + scb / 2;
      nxt0 = *(const bf16x8*)src;
      nxt1 = *(const bf16x8*)(src + 8);
    }

    // ---- Stage 1: 16 MFMA 32x32x16, zero-C on first kstep
    f32x16 acc[2];
    {
      f32x16 z;
#pragma unroll
      for (int i = 0; i < 16; ++i) z[i] = 0.f;
#pragma unroll
      for (int ks = 0; ks < 8; ++ks) {
        const int cb = (ks * 32 + (lh << 4)) ^ xorr;
        const bf16x8 Ah = *(const bf16x8*)&fh[cur][rowbase + (cb >> 1)];
        if (ks == 0) {
          acc[0] = __builtin_amdgcn_mfma_f32_32x32x16_bf16(Ah, Bq[0][0], z, 0, 0, 0);
          acc[1] = __builtin_amdgcn_mfma_f32_32x32x16_bf16(Ah, Bq[1][0], z, 0, 0, 0);
        } else {
          acc[0] = __builtin_amdgcn_mfma_f32_32x32x16_bf16(Ah, Bq[0][ks], acc[0], 0, 0, 0);
          acc[1] = __builtin_amdgcn_mfma_f32_32x32x16_bf16(Ah, Bq[1][ks], acc[1], 0, 0, 0);
        }
      }
    }

    // ---- cam A-frags under pi: per kstep two contiguous b64 loads
    bf16x8 Ac[2];
#pragma unroll
    for (int kst = 0; kst < 2; ++kst) {
      union { short4v h[2]; bf16x8 v; } A;
      const u16* cp = camA + ((size_t)n * 32 + l31) * HW64 + p0 + kst * 16 + lh * 4;
      A.h[0] = *(const short4v*)cp;
      A.h[1] = *(const short4v*)(cp + 8);
      Ac[kst] = A.v;
    }

    // ---- Stage 2: B-frag = own acc regs (relu+pack), 4 MFMA 32x32x16
#pragma unroll
    for (int qh = 0; qh < 2; ++qh) {
      union { u32 d[4]; bf16x8 v; } W0, W1;
#pragma unroll
      for (int i = 0; i < 4; ++i) {
        const float a0 = fmaxf(acc[qh][2 * i], 0.f);
        const float a1 = fmaxf(acc[qh][2 * i + 1], 0.f);
        asm("v_cvt_pk_bf16_f32 %0, %1, %2" : "=v"(W0.d[i]) : "v"(a0), "v"(a1));
        const float b0 = fmaxf(acc[qh][8 + 2 * i], 0.f);
        const float b1 = fmaxf(acc[qh][8 + 2 * i + 1], 0.f);
        asm("v_cvt_pk_bf16_f32 %0, %1, %2" : "=v"(W1.d[i]) : "v"(b0), "v"(b1));
      }
      nacc[qh] = __builtin_amdgcn_mfma_f32_32x32x16_bf16(Ac[0], W0.v, nacc[qh], 0, 0, 0);
      nacc[qh] = __builtin_amdgcn_mfma_f32_32x32x16_bf16(Ac[1], W1.v, nacc[qh], 0, 0, 0);
    }

    // ---- late ds_write of next tile
    if (t < 31) {
      *(bf16x8*)&fh[cur ^ 1][w0] = nxt0;
      *(bf16x8*)&fh[cur ^ 1][w1] = nxt1;
    }
    cur ^= 1;
  }

  // ---- epilogue: row = (r&3)+8*(r>>2)+4*lh (<22), col q = qb+wq*64+qh*32+l31
#pragma unroll
  for (int qh = 0; qh < 2; ++qh) {
    const int qg = qb + wq * 64 + qh * 32 + l31;
#pragma unroll
    for (int r = 0; r < 16; ++r) {
      const int row = (r & 3) + 8 * (r >> 2) + 4 * lh;
      if (row < 22)
        part[(((size_t)n * PSPLIT + ps) * 22 + row) * HW64 + qg] = nacc[qh][r];
    }
  }
}

// ---------------------------------------------------------------------------
// Kernel D: combine PSPLIT partials, divide.
// ---------------------------------------------------------------------------
__global__ __launch_bounds__(256) void k_final(
    const float* __restrict__ part, float* __restrict__ out, int total)
{
  const int idx = blockIdx.x * 256 + threadIdx.x;
  if (idx >= total) return;
  const int n = idx / (KCAM * HW64);
  const int r = idx - n * (KCAM * HW64);
  const int k = r >> 12;
  const int q = r & 4095;
  const float* base = part + (size_t)n * PSPLIT * 22 * HW64;
  float num = 0.f, den = 0.f;
#pragma unroll
  for (int p = 0; p < PSPLIT; ++p) {
    num += base[((size_t)p * 22 + k) * HW64 + q];
    den += base[((size_t)p * 22 + 21) * HW64 + q];
  }
  out[idx] = num / (den + 1e-5f);
}

// ---------------------------------------------------------------------------
extern "C" void kernel_launch(void* const* d_in, const int* in_sizes, int n_in,
                              void* d_out, int out_size, void* d_ws, size_t ws_size,
                              hipStream_t stream) {
  const float* aspp   = (const float*)d_in[0];
  const float* f3     = (const float*)d_in[1];
  const float* inp    = (const float*)d_in[2];
  const float* cam    = (const float*)d_in[3];
  const float* w_aspp = (const float*)d_in[4];
  const float* w_f3   = (const float*)d_in[5];
  const float* w_f9   = (const float*)d_in[6];
  float* out = (float*)d_out;

  // Workspace (~21.7 MB):
  //   [0, 8MB)       fhi  (u16, 8*4096*128)   k_build_f
  //   [8MB, 10MB)    camA (u16, 8*32*4096)    k_build_f side job
  //   [+80KB, +80KB) whi/wlo (u16, 128*160)   k_conv32 side job
  //   then part (f32, 8*4*22*4096 = 11.5MB)   k_fused
  //   a32/g32 (2MB each) ALIAS part (dead before k_fused; stream-ordered).
  u16*   fhi  = (u16*)d_ws;
  u16*   camA = fhi + 4194304;
  u16*   whi  = camA + 1048576;
  u16*   wlo  = whi + 20480;
  float* part = (float*)(wlo + 20480);
  float* a32  = part;
  float* g32  = a32 + 524288;

  k_conv32<<<dim3(4, 4, 8), 256, 0, stream>>>(aspp, f3, w_aspp, w_f3, w_f9,
                                              a32, g32, whi, wlo);
  k_build_f<<<dim3(32, 8), 256, 0, stream>>>(inp, a32, g32, whi, wlo, cam,
                                             fhi, camA);
  k_fused<<<512, 256, 0, stream>>>(fhi, camA, part);
  k_final<<<2688, 256, 0, stream>>>(part, out, 8 * KCAM * HW64);
}

// Round 13
// 102.862 us; speedup vs baseline: 1.4212x; 1.0916x over previous
//
#include <hip/hip_runtime.h>
#include <math.h>

typedef unsigned short u16;
typedef unsigned int u32;
typedef __attribute__((ext_vector_type(8))) short bf16x8;
typedef __attribute__((ext_vector_type(4))) short short4v;
typedef __attribute__((ext_vector_type(4))) float f32x4;
typedef __attribute__((ext_vector_type(16))) float f32x16;

#define HW32 1024
#define HW64 4096
#define KCAM 21
#define PB 64
#define PSPLIT 4
#define FT_STR 168   // u16 LDS row stride for feat (160 + 8 pad)

static __device__ __forceinline__ u16 f2bf(float x) {
  u32 u = __float_as_uint(x);
  u32 r = (u + 0x7FFFu + ((u >> 16) & 1u)) >> 16;
  return (u16)r;
}
static __device__ __forceinline__ float bf2f(u16 h) {
  return __uint_as_float(((u32)h) << 16);
}

// ---------------------------------------------------------------------------
// Kernel A: 1x1 convs at 32x32 (f32). grid (4 ptiles, 2 which x 4 jq, 8 n)
// = 256 blocks (16 out-ch each). Side job (blockIdx.y==0): split w_f9 into
// padded bf16 hi/lo [128][160].
// ---------------------------------------------------------------------------
__global__ __launch_bounds__(256) void k_conv32(
    const float* __restrict__ aspp, const float* __restrict__ f3,
    const float* __restrict__ w_aspp, const float* __restrict__ w_f3,
    const float* __restrict__ w_f9,
    float* __restrict__ a32, float* __restrict__ g32,
    u16* __restrict__ whi, u16* __restrict__ wlo)
{
  const int pt = blockIdx.x, which = blockIdx.y >> 2, jq = blockIdx.y & 3,
            n = blockIdx.z;

  if (blockIdx.y == 0) {   // w_f9 split side job
    const int bid = blockIdx.z * 4 + blockIdx.x;
#pragma unroll
    for (int k = 0; k < 3; ++k) {
      const int idx = bid * 256 + threadIdx.x + k * 8192;
      if (idx < 128 * 160) {
        const int o = idx / 160, c = idx - o * 160;
        const float v = (c < 132) ? w_f9[o * 132 + c] : 0.f;
        const u16 h = f2bf(v);
        whi[idx] = h;
        wlo[idx] = f2bf(v - bf2f(h));
      }
    }
  }

  const float* x = (which == 0 ? aspp : f3) + (size_t)n * 128 * HW32;
  const float* w = (which == 0 ? w_aspp : w_f3) + jq * 16 * 128;
  float* out = (which == 0 ? a32 : g32) + (size_t)n * 64 * HW32 + (size_t)jq * 16 * HW32;

  __shared__ __align__(16) float wlds[16 * 128];
  for (int i = threadIdx.x; i < 16 * 128; i += 256) wlds[i] = w[i];
  __syncthreads();

  const int p = pt * 256 + threadIdx.x;
  float acc[16];
#pragma unroll
  for (int j = 0; j < 16; ++j) acc[j] = 0.f;

  for (int c0 = 0; c0 < 128; c0 += 8) {
    float xv[8];
#pragma unroll
    for (int cc = 0; cc < 8; ++cc) xv[cc] = x[(size_t)(c0 + cc) * HW32 + p];
#pragma unroll
    for (int j = 0; j < 16; ++j) {
      const float4 w0 = *reinterpret_cast<const float4*>(&wlds[j * 128 + c0]);
      const float4 w1 = *reinterpret_cast<const float4*>(&wlds[j * 128 + c0 + 4]);
      acc[j] = fmaf(w0.x, xv[0], acc[j]);
      acc[j] = fmaf(w0.y, xv[1], acc[j]);
      acc[j] = fmaf(w0.z, xv[2], acc[j]);
      acc[j] = fmaf(w0.w, xv[3], acc[j]);
      acc[j] = fmaf(w1.x, xv[4], acc[j]);
      acc[j] = fmaf(w1.y, xv[5], acc[j]);
      acc[j] = fmaf(w1.z, xv[6], acc[j]);
      acc[j] = fmaf(w1.w, xv[7], acc[j]);
    }
  }
  for (int j = 0; j < 16; ++j) out[(size_t)j * HW32 + p] = acc[j];
}

// ---------------------------------------------------------------------------
// Kernel B: build normalized f via MFMA (unchanged from R12).
// ---------------------------------------------------------------------------
__global__ __launch_bounds__(256) void k_build_f(
    const float* __restrict__ inp, const float* __restrict__ a32,
    const float* __restrict__ g32, const u16* __restrict__ whi,
    const u16* __restrict__ wlo, const float* __restrict__ cam,
    u16* __restrict__ fhi_g, u16* __restrict__ camA)
{
  const int y2 = blockIdx.x, n = blockIdx.y;
  const int tid = threadIdx.x;

  __shared__ __align__(16) u16 feat[128 * FT_STR];   // 42 KB

  {
    u16* dst = camA + ((size_t)n * 32 + y2) * HW64;
    if (y2 < KCAM) {
      const float* src = cam + ((size_t)n * KCAM + y2) * HW64;
      for (int i = tid; i < HW64; i += 256) dst[i] = f2bf(src[i]);
    } else {
      const u16 v = (y2 == KCAM) ? f2bf(1.f) : (u16)0;
      for (int i = tid; i < HW64; i += 256) dst[i] = v;
    }
  }

  const float s512 = 511.f / 63.f, s32 = 31.f / 63.f;
  const int yA0i = y2 * 2, yA1i = y2 * 2 + 1;
  const float sA0 = yA0i * s512, sA1 = yA1i * s512;
  const int y0A0 = (int)sA0, y0A1 = (int)sA1;
  const float wyA0 = sA0 - y0A0, wyA1 = sA1 - y0A1;
  const int y1A0 = min(y0A0 + 1, 511), y1A1 = min(y0A1 + 1, 511);
  const float sB0 = yA0i * s32, sB1 = yA1i * s32;
  const int y0B0 = (int)sB0, y0B1 = (int)sB1;
  const float wyB0 = sB0 - y0B0, wyB1 = sB1 - y0B1;
  const int y1B0 = min(y0B0 + 1, 31), y1B1 = min(y0B1 + 1, 31);

  for (int idx = tid; idx < 132 * 128; idx += 256) {
    const int c = idx >> 7;
    const int pos = idx & 127;
    const int ly = pos >> 6, x = pos & 63;
    const int y0A = ly ? y0A1 : y0A0, y1A = ly ? y1A1 : y1A0;
    const float wyA = ly ? wyA1 : wyA0;
    const int y0B = ly ? y0B1 : y0B0, y1B = ly ? y1B1 : y1B0;
    const float wyB = ly ? wyB1 : wyB0;
    float v;
    if (c < 4) {
      const float sx = x * s512;
      const int x0 = (int)sx;
      const float wx = sx - (float)x0;
      const int x1 = min(x0 + 1, 511);
      const float* im = inp + (size_t)(n * 4 + c) * 512 * 512;
      const float v00 = im[y0A * 512 + x0], v01 = im[y0A * 512 + x1];
      const float v10 = im[y1A * 512 + x0], v11 = im[y1A * 512 + x1];
      v = (v00 * (1.f - wx) + v01 * wx) * (1.f - wyA) +
          (v10 * (1.f - wx) + v11 * wx) * wyA;
    } else {
      const float* im = (c < 68) ? a32 + (size_t)(n * 64 + (c - 4)) * HW32
                                 : g32 + (size_t)(n * 64 + (c - 68)) * HW32;
      const float sx = x * s32;
      const int x0 = (int)sx;
      const float wx = sx - (float)x0;
      const int x1 = min(x0 + 1, 31);
      const float v00 = im[y0B * 32 + x0], v01 = im[y0B * 32 + x1];
      const float v10 = im[y1B * 32 + x0], v11 = im[y1B * 32 + x1];
      v = (v00 * (1.f - wx) + v01 * wx) * (1.f - wyB) +
          (v10 * (1.f - wx) + v11 * wx) * wyB;
    }
    feat[pos * FT_STR + c] = f2bf(v);
  }
  for (int idx = tid; idx < 28 * 128; idx += 256) {
    const int c = 132 + (idx >> 7), pos = idx & 127;
    feat[pos * FT_STR + c] = 0;
  }
  __syncthreads();

  const int lane = tid & 63, wave = tid >> 6;
  const int l15 = lane & 15, l4 = lane >> 4;

  f32x4 acc[8][2];
#pragma unroll
  for (int m = 0; m < 8; ++m)
#pragma unroll
    for (int nf = 0; nf < 2; ++nf) acc[m][nf] = {0.f, 0.f, 0.f, 0.f};

#pragma unroll
  for (int s = 0; s < 5; ++s) {
    bf16x8 B[2];
#pragma unroll
    for (int nf = 0; nf < 2; ++nf)
      B[nf] = *(const bf16x8*)&feat[(wave * 32 + nf * 16 + l15) * FT_STR +
                                    s * 32 + l4 * 8];
#pragma unroll
    for (int m = 0; m < 8; ++m) {
      const int wo = (m * 16 + l15) * 160 + s * 32 + l4 * 8;
      const bf16x8 Ahi = *(const bf16x8*)(whi + wo);
      const bf16x8 Alo = *(const bf16x8*)(wlo + wo);
#pragma unroll
      for (int nf = 0; nf < 2; ++nf) {
        acc[m][nf] = __builtin_amdgcn_mfma_f32_16x16x32_bf16(Ahi, B[nf], acc[m][nf], 0, 0, 0);
        acc[m][nf] = __builtin_amdgcn_mfma_f32_16x16x32_bf16(Alo, B[nf], acc[m][nf], 0, 0, 0);
      }
    }
  }

#pragma unroll
  for (int nf = 0; nf < 2; ++nf) {
    float ss = 0.f;
#pragma unroll
    for (int m = 0; m < 8; ++m)
#pragma unroll
      for (int i = 0; i < 4; ++i) ss = fmaf(acc[m][nf][i], acc[m][nf][i], ss);
    ss += __shfl_xor(ss, 16);
    ss += __shfl_xor(ss, 32);
    const float inv = 1.f / (sqrtf(ss) + 1e-5f);
    const int pos = wave * 32 + nf * 16 + l15;
    u16* fp = fhi_g + ((size_t)n * HW64 + (size_t)(y2 * 2 + (pos >> 6)) * 64 +
                       (pos & 63)) * 128 + l4 * 4;
#pragma unroll
    for (int m = 0; m < 8; ++m) {
      const float v0 = acc[m][nf][0] * inv, v1 = acc[m][nf][1] * inv;
      const float v2 = acc[m][nf][2] * inv, v3 = acc[m][nf][3] * inv;
      union { u32 d[2]; short4v h; } P;
      asm("v_cvt_pk_bf16_f32 %0, %1, %2" : "=v"(P.d[0]) : "v"(v0), "v"(v1));
      asm("v_cvt_pk_bf16_f32 %0, %1, %2" : "=v"(P.d[1]) : "v"(v2), "v"(v3));
      *(short4v*)(fp + m * 16) = P.h;
    }
  }
}

// ---------------------------------------------------------------------------
// Kernel C: fused affinity+cam on 32x32x16 MFMA, zero-shuffle stage-2,
// PB=64 (2 stage-1 M-tiles per wave; stage-2 K=64 in 4 ksteps).
// Stage-2 B-frag for kstep kst = own acc regs accS[kst>>1][qh][(kst&1)*8..+8]
// (relu+cvt_pk, zero cross-lane); cam A-frag absorbs pi as contiguous b64s.
// Block 256 thr / 4 waves (q64 each); PSPLIT=4; grid 512 = 4ps x 16qt x 8n.
// XOR-swizzled double-buffered LDS, one barrier/tile, async-split staging.
// part layout: [n][ps][22][4096].
// ---------------------------------------------------------------------------
__global__ __launch_bounds__(256) void k_fused(
    const u16* __restrict__ fhi_g, const u16* __restrict__ camA,
    float* __restrict__ part)
{
  __shared__ __align__(16) u16 fh[2][PB * 128];   // 32 KB, XOR-swizzled

  const int gx = blockIdx.x;
  const int n = gx & 7;
  const int rest = gx >> 3;
  const int qt = rest & 15;
  const int ps = rest >> 4;
  const int tid = threadIdx.x;
  const int lane = tid & 63;
  const int wq = tid >> 6;
  const int l31 = lane & 31;
  const int lh = lane >> 5;            // 0/1
  const int qb = qt * 256;

  const u16* fbase = fhi_g + (size_t)n * HW64 * 128;

  // q-side F fragments (B operand), resident: 64 VGPRs
  bf16x8 Bq[2][8];
#pragma unroll
  for (int qh = 0; qh < 2; ++qh) {
    const size_t rowo = (size_t)(qb + wq * 64 + qh * 32 + l31) * 128;
#pragma unroll
    for (int ks = 0; ks < 8; ++ks)
      Bq[qh][ks] = *(const bf16x8*)(fbase + rowo + ks * 16 + lh * 8);
  }

  f32x16 nacc0, nacc1;
#pragma unroll
  for (int i = 0; i < 16; ++i) { nacc0[i] = 0.f; nacc1[i] = 0.f; }

  const int p_base = ps * (HW64 / PSPLIT);
  // staging: thread owns 64B of row sp (0..63): four swizzled 16B chunks
  const int sp = tid >> 2;
  const int scb = (tid & 3) * 64;                  // byte col base
  const int xorw = (sp & 7) << 4;
  int wofs[4];
#pragma unroll
  for (int k = 0; k < 4; ++k)
    wofs[k] = sp * 128 + (((scb + k * 16) ^ xorw) >> 1);
  const int xorr = (l31 & 7) << 4;

  // prologue: stage tile 0 into buf 0
  {
    const u16* src = fbase + (size_t)(p_base + sp) * 128 + scb / 2;
#pragma unroll
    for (int k = 0; k < 4; ++k)
      *(bf16x8*)&fh[0][wofs[k]] = *(const bf16x8*)(src + k * 8);
  }

  int cur = 0;
  for (int t = 0; t < (HW64 / PSPLIT) / PB; ++t) {   // 16 tiles
    const int p0 = p_base + t * PB;
    __syncthreads();

    bf16x8 nxt[4];
    if (t < 15) {
      const u16* src = fbase + (size_t)(p0 + PB + sp) * 128 + scb / 2;
#pragma unroll
      for (int k = 0; k < 4; ++k) nxt[k] = *(const bf16x8*)(src + k * 8);
    }

    // ---- Stage 1: S[64p x 64q] per wave = 32 MFMA 32x32x16
    f32x16 accS[2][2];
#pragma unroll
    for (int ks = 0; ks < 8; ++ks) {
      const int cb = (ks * 32 + (lh << 4)) ^ xorr;
      bf16x8 Ah[2];
#pragma unroll
      for (int mt = 0; mt < 2; ++mt)
        Ah[mt] = *(const bf16x8*)&fh[cur][(mt * 32 + l31) * 128 + (cb >> 1)];
      if (ks == 0) {
        f32x16 z;
#pragma unroll
        for (int i = 0; i < 16; ++i) z[i] = 0.f;
#pragma unroll
        for (int mt = 0; mt < 2; ++mt) {
          accS[mt][0] = __builtin_amdgcn_mfma_f32_32x32x16_bf16(Ah[mt], Bq[0][0], z, 0, 0, 0);
          accS[mt][1] = __builtin_amdgcn_mfma_f32_32x32x16_bf16(Ah[mt], Bq[1][0], z, 0, 0, 0);
        }
      } else {
#pragma unroll
        for (int mt = 0; mt < 2; ++mt) {
          accS[mt][0] = __builtin_amdgcn_mfma_f32_32x32x16_bf16(Ah[mt], Bq[0][ks], accS[mt][0], 0, 0, 0);
          accS[mt][1] = __builtin_amdgcn_mfma_f32_32x32x16_bf16(Ah[mt], Bq[1][ks], accS[mt][1], 0, 0, 0);
        }
      }
    }

    // ---- cam A-frags under pi: per kstep two contiguous b64 loads
    bf16x8 Ac[4];
#pragma unroll
    for (int kst = 0; kst < 4; ++kst) {
      union { short4v h[2]; bf16x8 v; } A;
      const u16* cp = camA + ((size_t)n * 32 + l31) * HW64 + p0 + kst * 16 + lh * 4;
      A.h[0] = *(const short4v*)cp;
      A.h[1] = *(const short4v*)(cp + 8);
      Ac[kst] = A.v;
    }

    // ---- Stage 2: B-frag = own acc regs (relu+pack), 8 MFMA 32x32x16
#pragma unroll
    for (int kst = 0; kst < 4; ++kst) {
      const int mt = kst >> 1, h8 = (kst & 1) * 8;
#pragma unroll
      for (int qh = 0; qh < 2; ++qh) {
        union { u32 d[4]; bf16x8 v; } W;
#pragma unroll
        for (int i = 0; i < 4; ++i) {
          const float a0 = fmaxf(accS[mt][qh][h8 + 2 * i], 0.f);
          const float a1 = fmaxf(accS[mt][qh][h8 + 2 * i + 1], 0.f);
          asm("v_cvt_pk_bf16_f32 %0, %1, %2" : "=v"(W.d[i]) : "v"(a0), "v"(a1));
        }
        if (qh == 0)
          nacc0 = __builtin_amdgcn_mfma_f32_32x32x16_bf16(Ac[kst], W.v, nacc0, 0, 0, 0);
        else
          nacc1 = __builtin_amdgcn_mfma_f32_32x32x16_bf16(Ac[kst], W.v, nacc1, 0, 0, 0);
      }
    }

    // ---- late ds_write of next tile
    if (t < 15) {
#pragma unroll
      for (int k = 0; k < 4; ++k) *(bf16x8*)&fh[cur ^ 1][wofs[k]] = nxt[k];
    }
    cur ^= 1;
  }

  // ---- epilogue: row = (r&3)+8*(r>>2)+4*lh (<22), col q = qb+wq*64+qh*32+l31
#pragma unroll
  for (int qh = 0; qh < 2; ++qh) {
    const int qg = qb + wq * 64 + qh * 32 + l31;
#pragma unroll
    for (int r = 0; r < 16; ++r) {
      const int row = (r & 3) + 8 * (r >> 2) + 4 * lh;
      if (row < 22)
        part[(((size_t)n * PSPLIT + ps) * 22 + row) * HW64 + qg] =
            (qh == 0) ? nacc0[r] : nacc1[r];
    }
  }
}

// ---------------------------------------------------------------------------
// Kernel D: combine PSPLIT partials, divide.
// ---------------------------------------------------------------------------
__global__ __launch_bounds__(256) void k_final(
    const float* __restrict__ part, float* __restrict__ out, int total)
{
  const int idx = blockIdx.x * 256 + threadIdx.x;
  if (idx >= total) return;
  const int n = idx / (KCAM * HW64);
  const int r = idx - n * (KCAM * HW64);
  const int k = r >> 12;
  const int q = r & 4095;
  const float* base = part + (size_t)n * PSPLIT * 22 * HW64;
  float num = 0.f, den = 0.f;
#pragma unroll
  for (int p = 0; p < PSPLIT; ++p) {
    num += base[((size_t)p * 22 + k) * HW64 + q];
    den += base[((size_t)p * 22 + 21) * HW64 + q];
  }
  out[idx] = num / (den + 1e-5f);
}

// ---------------------------------------------------------------------------
extern "C" void kernel_launch(void* const* d_in, const int* in_sizes, int n_in,
                              void* d_out, int out_size, void* d_ws, size_t ws_size,
                              hipStream_t stream) {
  const float* aspp   = (const float*)d_in[0];
  const float* f3     = (const float*)d_in[1];
  const float* inp    = (const float*)d_in[2];
  const float* cam    = (const float*)d_in[3];
  const float* w_aspp = (const float*)d_in[4];
  const float* w_f3   = (const float*)d_in[5];
  const float* w_f9   = (const float*)d_in[6];
  float* out = (float*)d_out;

  // Workspace (~21.7 MB):
  //   [0, 8MB)       fhi  (u16, 8*4096*128)   k_build_f
  //   [8MB, 10MB)    camA (u16, 8*32*4096)    k_build_f side job
  //   [+80KB, +80KB) whi/wlo (u16, 128*160)   k_conv32 side job
  //   then part (f32, 8*4*22*4096 = 11.5MB)   k_fused
  //   a32/g32 (2MB each) ALIAS part (dead before k_fused; stream-ordered).
  u16*   fhi  = (u16*)d_ws;
  u16*   camA = fhi + 4194304;
  u16*   whi  = camA + 1048576;
  u16*   wlo  = whi + 20480;
  float* part = (float*)(wlo + 20480);
  float* a32  = part;
  float* g32  = a32 + 524288;

  k_conv32<<<dim3(4, 8, 8), 256, 0, stream>>>(aspp, f3, w_aspp, w_f3, w_f9,
                                              a32, g32, whi, wlo);
  k_build_f<<<dim3(32, 8), 256, 0, stream>>>(inp, a32, g32, whi, wlo, cam,
                                             fhi, camA);
  k_fused<<<512, 256, 0, stream>>>(fhi, camA, part);
  k_final<<<2688, 256, 0, stream>>>(part, out, 8 * KCAM * HW64);
}